// Round 7
// baseline (117.517 us; speedup 1.0000x reference)
//
#include <hip/hip_runtime.h>

#define D_ 8
#define B_ 32
#define PRE_ 1024
#define POST_ 1024

// exp(-1/10), exp(-1/20), exp(-1/15)
#define ALPHA_P 0.90483741803595952f
#define ALPHA_D 0.95122942450071400f
#define ALPHA_X 0.93550698503161731f

#define OHALF  (POST_ / 2)                                    // 512 columns per block
#define NMAIN  (PRE_ * 2)                                     // 2048 main blocks (e x o-half)
#define NFILT  (((D_*B_*PRE_)/4 + 2*((B_*POST_)/4)) / 256)    // 320 filter blocks

typedef float f32x4 __attribute__((ext_vector_type(4)));
typedef float f32x2 __attribute__((ext_vector_type(2)));

// Two blocks per e (o-halves of 512), all 32 b per block:
//   - dmap[.,e,ohalf] (16 KB) staged in LDS once -> reused 32x, cache-independent;
//     each half staged by exactly ONE block -> dmap HBM-fetched exactly once.
//   - LDS 18 KB/block -> 8 blocks/CU (144 KB) -> 32 waves/CU = 100% occupancy
//     (vs round 6's 34 KB -> 4 blocks -> 50%). f32x2 per thread keeps VGPR ~45-55,
//     under the 64-VGPR cliff (round 4: forced 32 = spill disaster; round 5:
//     squeezed 64 = mild spill; spill check = WRITE_SIZE stays ~263 MB).
//   - W NT-loaded (read-once) with 1-deep prefetch; out/W_new NT-stored so the
//     ~400 MB stream doesn't evict dmap/A_p/A_d/wmax slices.
__global__ __launch_bounds__(256, 4) void clopath_fused(
    const float* __restrict__ W,
    const float* __restrict__ dmap,
    const float* __restrict__ A_p,
    const float* __restrict__ A_d,
    const float* __restrict__ wmax,
    const float* __restrict__ xbar_pre,
    const float* __restrict__ Xd,
    const float* __restrict__ Xpost,
    const float* __restrict__ Vpost,
    const float* __restrict__ u_pot,
    const float* __restrict__ u_dep,
    float* __restrict__ out,       // output 0: copy of W
    float* __restrict__ W_new,     // output 1
    float* __restrict__ xbar_new,  // output 2
    float* __restrict__ u_pot_new, // output 3
    float* __restrict__ u_dep_new) // output 4
{
    const int bid = blockIdx.x;
    const int tid = threadIdx.x;

    if (bid < NMAIN) {
        const int e  = bid >> 1;               // 0..1023
        const int oh = bid & 1;                // which o-half
        const int o  = oh * OHALF + (tid << 1);  // this thread's 2 columns

        __shared__ float dm_lds[D_ * OHALF];    // 16 KB: dmap e-slice half
        __shared__ float xbd_lds[B_ * D_ * 2];  // 2 KB: interleaved (xb, xd) per (b,d)

        // Stage (xb, xd) pairs: t -> (b = t>>3, d = t&7)
        {
            const int d = tid & 7;
            const int b = tid >> 3;
            const size_t idx = ((size_t)(d * B_ + b)) * PRE_ + e;
            f32x2 p;
            p.x = xbar_pre[idx];
            p.y = Xd[idx];
            *reinterpret_cast<f32x2*>(&xbd_lds[(b * D_ + d) * 2]) = p;
        }
        // Stage dmap half-slice: thread t loads its 2 columns for each d (coalesced)
        #pragma unroll
        for (int d = 0; d < D_; ++d) {
            *reinterpret_cast<f32x2*>(&dm_lds[d * OHALF + (tid << 1)]) =
                *reinterpret_cast<const f32x2*>(
                    dmap + ((size_t)(d * PRE_ + e)) * POST_ + o);
        }
        __syncthreads();

        const f32x2 ap2 = *reinterpret_cast<const f32x2*>(A_p  + (size_t)e * POST_ + o);
        const f32x2 ad2 = *reinterpret_cast<const f32x2*>(A_d  + (size_t)e * POST_ + o);
        const f32x2 wm2 = *reinterpret_cast<const f32x2*>(wmax + (size_t)e * POST_ + o);

        // W row stride over b is PRE_*POST_; prefetch b=0
        size_t wi_nxt = (size_t)e * POST_ + o;
        f32x2 w_nxt = __builtin_nontemporal_load(
                          reinterpret_cast<const f32x2*>(W + wi_nxt));

        #pragma unroll 1
        for (int b = 0; b < B_; ++b) {
            const f32x2 w2 = w_nxt;
            const size_t wi = wi_nxt;
            if (b < B_ - 1) {   // uniform branch; 1-deep W prefetch
                wi_nxt += (size_t)PRE_ * POST_;
                w_nxt = __builtin_nontemporal_load(
                            reinterpret_cast<const f32x2*>(W + wi_nxt));
            }

            const size_t go = (size_t)b * POST_ + o;
            const f32x2 xp2 = *reinterpret_cast<const f32x2*>(Xpost + go);
            const f32x2 up2 = *reinterpret_cast<const f32x2*>(u_pot + go);
            const f32x2 ud2 = *reinterpret_cast<const f32x2*>(u_dep + go);

            f32x2 sp = {0.f, 0.f};
            f32x2 sd = {0.f, 0.f};
            #pragma unroll
            for (int d = 0; d < D_; ++d) {
                // uniform-address b64 broadcast: (xb, xd) for this (b,d)
                const f32x2 xbd = *reinterpret_cast<const f32x2*>(
                                      &xbd_lds[(b * D_ + d) * 2]);
                // per-thread contiguous b64 read of dmap columns
                const f32x2 dm = *reinterpret_cast<const f32x2*>(
                                      &dm_lds[d * OHALF + (tid << 1)]);
                sp.x = fmaf(xbd.x, dm.x, sp.x);
                sp.y = fmaf(xbd.x, dm.y, sp.y);
                sd.x = fmaf(xbd.y, dm.x, sd.x);
                sd.y = fmaf(xbd.y, dm.y, sd.y);
            }

            f32x2 nv;
            {
                const float gpx = xp2.x * fmaxf(up2.x, 0.f);
                const float gpy = xp2.y * fmaxf(up2.y, 0.f);
                const float gdx = fmaxf(ud2.x, 0.f);
                const float gdy = fmaxf(ud2.y, 0.f);
                float wnx = w2.x + sp.x * ap2.x * gpx - sd.x * ad2.x * gdx;
                float wny = w2.y + sp.y * ap2.y * gpy - sd.y * ad2.y * gdy;
                nv.x = fminf(wm2.x, fmaxf(wnx, 0.f));
                nv.y = fminf(wm2.y, fmaxf(wny, 0.f));
            }
            __builtin_nontemporal_store(w2, reinterpret_cast<f32x2*>(out   + wi));
            __builtin_nontemporal_store(nv, reinterpret_cast<f32x2*>(W_new + wi));
        }
    } else {
        // ---- filter tail: elementwise exponential filters ----
        const int i = (bid - NMAIN) * 256 + tid;   // float4 index
        const int NX = (D_ * B_ * PRE_) / 4;       // 65536
        const int NU = (B_ * POST_) / 4;           // 8192

        if (i < NX) {
            f32x4 a = *reinterpret_cast<const f32x4*>(xbar_pre + (size_t)i * 4);
            f32x4 b = *reinterpret_cast<const f32x4*>(Xd       + (size_t)i * 4);
            f32x4 r = ALPHA_X * a + (1.0f - ALPHA_X) * b;
            __builtin_nontemporal_store(r, reinterpret_cast<f32x4*>(xbar_new + (size_t)i * 4));
        } else if (i < NX + NU) {
            const int j = i - NX;
            f32x4 a = *reinterpret_cast<const f32x4*>(u_pot + (size_t)j * 4);
            f32x4 b = *reinterpret_cast<const f32x4*>(Vpost + (size_t)j * 4);
            f32x4 r = ALPHA_P * a + (1.0f - ALPHA_P) * b;
            __builtin_nontemporal_store(r, reinterpret_cast<f32x4*>(u_pot_new + (size_t)j * 4));
        } else {
            const int j = i - NX - NU;
            f32x4 a = *reinterpret_cast<const f32x4*>(u_dep + (size_t)j * 4);
            f32x4 b = *reinterpret_cast<const f32x4*>(Vpost + (size_t)j * 4);
            f32x4 r = ALPHA_D * a + (1.0f - ALPHA_D) * b;
            __builtin_nontemporal_store(r, reinterpret_cast<f32x4*>(u_dep_new + (size_t)j * 4));
        }
    }
}

extern "C" void kernel_launch(void* const* d_in, const int* in_sizes, int n_in,
                              void* d_out, int out_size, void* d_ws, size_t ws_size,
                              hipStream_t stream) {
    const float* Xd       = (const float*)d_in[0];
    const float* Xpost    = (const float*)d_in[1];
    const float* Vpost    = (const float*)d_in[2];
    const float* W        = (const float*)d_in[3];
    const float* xbar_pre = (const float*)d_in[4];
    const float* u_pot    = (const float*)d_in[5];
    const float* u_dep    = (const float*)d_in[6];
    const float* dmap     = (const float*)d_in[7];
    const float* A_p      = (const float*)d_in[8];
    const float* A_d      = (const float*)d_in[9];
    const float* wmax     = (const float*)d_in[10];

    float* out        = (float*)d_out;
    float* W_new      = out + (size_t)B_ * PRE_ * POST_;
    float* xbar_new   = W_new + (size_t)B_ * PRE_ * POST_;
    float* u_pot_new  = xbar_new + (size_t)D_ * B_ * PRE_;
    float* u_dep_new  = u_pot_new + (size_t)B_ * POST_;

    clopath_fused<<<NMAIN + NFILT, 256, 0, stream>>>(
        W, dmap, A_p, A_d, wmax, xbar_pre, Xd, Xpost, Vpost, u_pot, u_dep,
        out, W_new, xbar_new, u_pot_new, u_dep_new);
}

// Round 8
// 107.127 us; speedup vs baseline: 1.0970x; 1.0970x over previous
//
#include <hip/hip_runtime.h>

#define D_ 8
#define B_ 32
#define PRE_ 1024
#define POST_ 1024

// exp(-1/10), exp(-1/20), exp(-1/15)
#define ALPHA_P 0.90483741803595952f
#define ALPHA_D 0.95122942450071400f
#define ALPHA_X 0.93550698503161731f

#define NMAIN PRE_                                            // 1024 main blocks
#define NFILT (((D_*B_*PRE_)/4 + 2*((B_*POST_)/4)) / 256)     // 320 filter blocks

typedef float f32x4 __attribute__((ext_vector_type(4)));
typedef float f32x2 __attribute__((ext_vector_type(2)));

// Round-6 structure (best so far) + full register pipelining of per-iter loads.
//   - One block per e, 256 threads, f32x4 per thread (16 B/lane — round 7 proved
//     8 B/lane costs ~10% via doubled instruction overhead).
//   - dmap[.,e,.] (32 KB) staged in LDS once -> reused 32x, cache-independent.
//   - LDS 34 KB -> 4 blocks/CU = 16 waves/CU is the occupancy cap -> VGPR up to
//     128 is FREE. __launch_bounds__(256,2) caps at 128; natural use ~75-90.
//     (Round 4: forced 32 = disaster spill; round 5: squeezed 64 = mild spill.
//      Spill check: WRITE_SIZE must stay ~263 MB.)
//   - Software pipeline: W (NT) + Xpost/u_pot/u_dep loaded one b-iteration ahead
//     into registers, so compute of iter b covers the ~300-900 cy latency of
//     iter b+1's loads. out/W_new NT-stored (write-once streams).
__global__ __launch_bounds__(256, 2) void clopath_fused(
    const float* __restrict__ W,
    const float* __restrict__ dmap,
    const float* __restrict__ A_p,
    const float* __restrict__ A_d,
    const float* __restrict__ wmax,
    const float* __restrict__ xbar_pre,
    const float* __restrict__ Xd,
    const float* __restrict__ Xpost,
    const float* __restrict__ Vpost,
    const float* __restrict__ u_pot,
    const float* __restrict__ u_dep,
    float* __restrict__ out,       // output 0: copy of W
    float* __restrict__ W_new,     // output 1
    float* __restrict__ xbar_new,  // output 2
    float* __restrict__ u_pot_new, // output 3
    float* __restrict__ u_dep_new) // output 4
{
    const int bid = blockIdx.x;
    const int tid = threadIdx.x;

    if (bid < NMAIN) {
        const int e = bid;                 // one block per e
        const int o = tid << 2;            // this thread's float4 of POST

        __shared__ float dm_lds[D_ * POST_];   // 32 KB: dmap e-slice
        __shared__ float xbd_lds[B_ * D_ * 2]; // 2 KB: interleaved (xb, xd) per (b,d)

        // Stage (xb, xd) pairs: t -> (b = t>>3, d = t&7)
        {
            const int d = tid & 7;
            const int b = tid >> 3;
            const size_t idx = ((size_t)(d * B_ + b)) * PRE_ + e;
            f32x2 p;
            p.x = xbar_pre[idx];
            p.y = Xd[idx];
            *reinterpret_cast<f32x2*>(&xbd_lds[(b * D_ + d) * 2]) = p;
        }
        // Stage dmap e-slice: thread t loads its own 4 columns for each d (coalesced)
        #pragma unroll
        for (int d = 0; d < D_; ++d) {
            *reinterpret_cast<f32x4*>(&dm_lds[d * POST_ + o]) =
                *reinterpret_cast<const f32x4*>(
                    dmap + ((size_t)(d * PRE_ + e)) * POST_ + o);
        }
        __syncthreads();

        const f32x4 ap4 = *reinterpret_cast<const f32x4*>(A_p  + (size_t)e * POST_ + o);
        const f32x4 ad4 = *reinterpret_cast<const f32x4*>(A_d  + (size_t)e * POST_ + o);
        const f32x4 wm4 = *reinterpret_cast<const f32x4*>(wmax + (size_t)e * POST_ + o);

        // ---- software pipeline prologue: load iteration 0's operands ----
        size_t wi_cur = (size_t)e * POST_ + o;
        f32x4 w_cur  = __builtin_nontemporal_load(
                           reinterpret_cast<const f32x4*>(W + wi_cur));
        f32x4 xp_cur = *reinterpret_cast<const f32x4*>(Xpost + o);
        f32x4 up_cur = *reinterpret_cast<const f32x4*>(u_pot + o);
        f32x4 ud_cur = *reinterpret_cast<const f32x4*>(u_dep + o);

        #pragma unroll 1
        for (int b = 0; b < B_; ++b) {
            // ---- issue next iteration's loads first (latency overlapped) ----
            f32x4 w_nxt, xp_nxt, up_nxt, ud_nxt;
            const size_t wi_nxt = wi_cur + (size_t)PRE_ * POST_;
            if (b < B_ - 1) {   // uniform branch
                w_nxt  = __builtin_nontemporal_load(
                             reinterpret_cast<const f32x4*>(W + wi_nxt));
                const size_t go_n = (size_t)(b + 1) * POST_ + o;
                xp_nxt = *reinterpret_cast<const f32x4*>(Xpost + go_n);
                up_nxt = *reinterpret_cast<const f32x4*>(u_pot + go_n);
                ud_nxt = *reinterpret_cast<const f32x4*>(u_dep + go_n);
            }

            // ---- compute iteration b from registers (no global wait) ----
            f32x4 sp = {0.f, 0.f, 0.f, 0.f};
            f32x4 sd = {0.f, 0.f, 0.f, 0.f};
            #pragma unroll
            for (int d = 0; d < D_; ++d) {
                const f32x2 xbd = *reinterpret_cast<const f32x2*>(
                                      &xbd_lds[(b * D_ + d) * 2]);   // b64 broadcast
                const f32x4 dm = *reinterpret_cast<const f32x4*>(
                                      &dm_lds[d * POST_ + o]);       // b128 per-thread
                #pragma unroll
                for (int j = 0; j < 4; ++j) {
                    sp[j] = fmaf(xbd.x, dm[j], sp[j]);
                    sd[j] = fmaf(xbd.y, dm[j], sd[j]);
                }
            }

            f32x4 nv;
            #pragma unroll
            for (int j = 0; j < 4; ++j) {
                const float gp = xp_cur[j] * fmaxf(up_cur[j], 0.f);  // Xpost*relu(u_pot)
                const float gd = fmaxf(ud_cur[j], 0.f);              // relu(u_dep)
                float wn = w_cur[j] + sp[j] * ap4[j] * gp - sd[j] * ad4[j] * gd;
                nv[j] = fminf(wm4[j], fmaxf(wn, 0.f));
            }
            __builtin_nontemporal_store(w_cur, reinterpret_cast<f32x4*>(out   + wi_cur));
            __builtin_nontemporal_store(nv,    reinterpret_cast<f32x4*>(W_new + wi_cur));

            // ---- rotate pipeline registers ----
            wi_cur = wi_nxt;
            w_cur  = w_nxt;
            xp_cur = xp_nxt;
            up_cur = up_nxt;
            ud_cur = ud_nxt;
        }
    } else {
        // ---- filter tail: elementwise exponential filters ----
        const int i = (bid - NMAIN) * 256 + tid;   // float4 index
        const int NX = (D_ * B_ * PRE_) / 4;       // 65536
        const int NU = (B_ * POST_) / 4;           // 8192

        if (i < NX) {
            f32x4 a = *reinterpret_cast<const f32x4*>(xbar_pre + (size_t)i * 4);
            f32x4 b = *reinterpret_cast<const f32x4*>(Xd       + (size_t)i * 4);
            f32x4 r = ALPHA_X * a + (1.0f - ALPHA_X) * b;
            __builtin_nontemporal_store(r, reinterpret_cast<f32x4*>(xbar_new + (size_t)i * 4));
        } else if (i < NX + NU) {
            const int j = i - NX;
            f32x4 a = *reinterpret_cast<const f32x4*>(u_pot + (size_t)j * 4);
            f32x4 b = *reinterpret_cast<const f32x4*>(Vpost + (size_t)j * 4);
            f32x4 r = ALPHA_P * a + (1.0f - ALPHA_P) * b;
            __builtin_nontemporal_store(r, reinterpret_cast<f32x4*>(u_pot_new + (size_t)j * 4));
        } else {
            const int j = i - NX - NU;
            f32x4 a = *reinterpret_cast<const f32x4*>(u_dep + (size_t)j * 4);
            f32x4 b = *reinterpret_cast<const f32x4*>(Vpost + (size_t)j * 4);
            f32x4 r = ALPHA_D * a + (1.0f - ALPHA_D) * b;
            __builtin_nontemporal_store(r, reinterpret_cast<f32x4*>(u_dep_new + (size_t)j * 4));
        }
    }
}

extern "C" void kernel_launch(void* const* d_in, const int* in_sizes, int n_in,
                              void* d_out, int out_size, void* d_ws, size_t ws_size,
                              hipStream_t stream) {
    const float* Xd       = (const float*)d_in[0];
    const float* Xpost    = (const float*)d_in[1];
    const float* Vpost    = (const float*)d_in[2];
    const float* W        = (const float*)d_in[3];
    const float* xbar_pre = (const float*)d_in[4];
    const float* u_pot    = (const float*)d_in[5];
    const float* u_dep    = (const float*)d_in[6];
    const float* dmap     = (const float*)d_in[7];
    const float* A_p      = (const float*)d_in[8];
    const float* A_d      = (const float*)d_in[9];
    const float* wmax     = (const float*)d_in[10];

    float* out        = (float*)d_out;
    float* W_new      = out + (size_t)B_ * PRE_ * POST_;
    float* xbar_new   = W_new + (size_t)B_ * PRE_ * POST_;
    float* u_pot_new  = xbar_new + (size_t)D_ * B_ * PRE_;
    float* u_dep_new  = u_pot_new + (size_t)B_ * POST_;

    clopath_fused<<<NMAIN + NFILT, 256, 0, stream>>>(
        W, dmap, A_p, A_d, wmax, xbar_pre, Xd, Xpost, Vpost, u_pot, u_dep,
        out, W_new, xbar_new, u_pot_new, u_dep_new);
}